// Round 4
// baseline (566.785 us; speedup 1.0000x reference)
//
#include <hip/hip_runtime.h>

#define NN 512
#define DD 128
#define PP (NN*NN)   // 262144 positions

typedef __attribute__((ext_vector_type(8))) short short8;
typedef __attribute__((ext_vector_type(4))) float floatx4;
typedef __attribute__((ext_vector_type(4))) unsigned int uintx4;
typedef __attribute__((ext_vector_type(2))) unsigned int uintx2;

__device__ float g_gw[640];    // [m][e]: sum_d ln_g[d]*W_m[d][e]  (bf16 W)
__device__ float g_bwt[640];   // [m][e]: sum_d ln_b[d]*W_m[d][e] + bias_m[e]

__device__ __forceinline__ unsigned short f2bf(float f) {
  unsigned int u = __float_as_uint(f);
  u += 0x7fffu + ((u >> 16) & 1u);          // RNE
  return (unsigned short)(u >> 16);
}
__device__ __forceinline__ float bf2f(unsigned short h) {
  return __uint_as_float(((unsigned int)h) << 16);
}
// packed f32x2 -> bf16x2 (hardware RNE), low half <- first arg
__device__ __forceinline__ unsigned int pkbf2(float lo, float hi) {
  unsigned int r;
  asm("v_cvt_pk_bf16_f32 %0, %1, %2" : "=v"(r) : "v"(lo), "v"(hi));
  return r;
}
__device__ __forceinline__ float sigm(float x) {
  return 1.f / (1.f + __expf(-x));
}

// async global->LDS, 16B per lane. LDS dest must be wave-uniform base + lane*16.
__device__ __forceinline__ void gload_lds16(const unsigned short* g, unsigned short* l) {
  __builtin_amdgcn_global_load_lds(
      (const __attribute__((address_space(1))) unsigned int*)g,
      (__attribute__((address_space(3))) unsigned int*)l, 16, 0, 0);
}

// ---------------- k0: weights f32 [d][e] -> bf16 [m][e][d] ----------------
__global__ void k0_prep(const float* __restrict__ wlp, const float* __restrict__ wlg,
                        const float* __restrict__ wrp, const float* __restrict__ wrg,
                        const float* __restrict__ wg,  const float* __restrict__ wo,
                        unsigned short* __restrict__ wt) {
  const float* src[6] = {wlp, wlg, wrp, wrg, wg, wo};
  int m = blockIdx.y;
  int idx = blockIdx.x * 256 + threadIdx.x;   // 0..16383
  int d = idx >> 7, e = idx & 127;
  wt[m * 16384 + e * 128 + d] = f2bf(src[m][d * 128 + e]);
}

// ---------------- k0b: LN-linearization constants ----------------------------
// gW[m][e] = sum_d ln_g[d] * bf16(W_m[d][e]); bwt[m][e] = sum_d ln_b[d]*W + bias
__global__ void k0b_gw(const float* __restrict__ lng, const float* __restrict__ lnb,
                       const unsigned short* __restrict__ wt,
                       const float* __restrict__ b_lp, const float* __restrict__ b_lg,
                       const float* __restrict__ b_rp, const float* __restrict__ b_rg,
                       const float* __restrict__ b_g) {
  int m = blockIdx.x;          // 0..4
  int e = threadIdx.x;         // 0..127
  const unsigned short* wcol = wt + m * 16384 + e * 128;  // contiguous in d
  float sg = 0.f, sb = 0.f;
  for (int d = 0; d < 128; ++d) {
    float wv = bf2f(wcol[d]);
    sg += lng[d] * wv;
    sb += lnb[d] * wv;
  }
  const float* bias = (m == 0) ? b_lp : (m == 1) ? b_lg : (m == 2) ? b_rp
                      : (m == 3) ? b_rg : b_g;
  g_gw[m * 128 + e] = sg;
  g_bwt[m * 128 + e] = sb + bias[e];
}

// ---------------- k1b: fused LN + projections -------------------------------
// unit 0: left_t[e][p], unit 1: right_bt[e][k*512+j], unit 2: gate_t[e][p]
// Stages bf16(pair * ln_g) into XOR-swizzled LDS while computing row stats
// (mu, rs) via shfl; GEMM on (x.g); epilogue applies rs*acc - rs*mu*gW + bWt.
// Weight B-fragments read directly from global (L2-resident, 192 KB total).
__launch_bounds__(512, 4)
__global__ void k1b_proj(const float* __restrict__ pair,
                         const float* __restrict__ pmask,
                         const float* __restrict__ lng,
                         const unsigned short* __restrict__ wt,
                         unsigned short* __restrict__ left_t,
                         unsigned short* __restrict__ right_bt,
                         unsigned short* __restrict__ gate_t) {
  __shared__ __align__(16) unsigned short Sm[17408];  // Abf(16384) / stg(17408)
  __shared__ float Rs[128], Rm[128], Mlds[128];
  unsigned int* AbfU = (unsigned int*)Sm;

  const int t = threadIdx.x;
  const int unit = blockIdx.y;
  const int q = blockIdx.x;

  int j0 = 0, kk = 0;
  long p0 = 0, soff;
  if (unit == 1) {
    j0 = (q >> 9) << 7; kk = q & 511;
    soff = (long)kk * NN + j0;
  } else {
    p0 = (long)q << 7;
    soff = p0;
  }
  auto arow = [&](int r) -> long {
    return (unit == 1) ? ((long)(j0 + r) * NN + kk) : (p0 + r);
  };

  if (unit < 2 && t < 128) Mlds[t] = pmask[arow(t)];

  // ---- stage pair -> bf16(x*g), swizzled 16B chunks; row stats via shfl ----
  const int sub = t & 31;            // float-quad slot within row
  const int rb = t >> 5;             // 0..15
  const floatx4 g4 = *(const floatx4*)(lng + sub * 4);
  #pragma unroll
  for (int pass = 0; pass < 8; ++pass) {
    int r = rb + 16 * pass;
    floatx4 v = *(const floatx4*)(pair + arow(r) * DD + sub * 4);
    float s  = v.x + v.y + v.z + v.w;
    float s2 = v.x * v.x + v.y * v.y + v.z * v.z + v.w * v.w;
    #pragma unroll
    for (int mm = 1; mm < 32; mm <<= 1) {
      s  += __shfl_xor(s, mm);
      s2 += __shfl_xor(s2, mm);
    }
    float mu = s * (1.f / 128.f);
    float rs = rsqrtf(s2 * (1.f / 128.f) - mu * mu + 1e-5f);
    if (sub == 0) { Rs[r] = rs; Rm[r] = rs * mu; }
    uintx2 o;
    o[0] = pkbf2(v.x * g4.x, v.y * g4.y);
    o[1] = pkbf2(v.z * g4.z, v.w * g4.w);
    int chunk = (sub >> 1) ^ (r & 7);           // 16B-chunk XOR swizzle
    *(uintx2*)&AbfU[r * 64 + chunk * 4 + (sub & 1) * 2] = o;
  }
  __syncthreads();

  const unsigned short* wA = wt + (unit == 0 ? 0 : unit == 1 ? 2 : 4) * 16384;
  const unsigned short* wB = wt + (unit == 0 ? 1 : 3) * 16384;  // unused unit 2

  const int lane = t & 63, w = t >> 6;            // 8 waves
  const int ln = lane & 15, q8 = lane >> 4;
  const int wm = (w >> 2) << 6, we = (w & 3) << 5; // 64x32 per-wave tile

  floatx4 aP[4][2] = {}, aG[4][2] = {};
  #pragma unroll
  for (int kc = 0; kc < 4; ++kc) {
    short8 a[4];
    #pragma unroll
    for (int i = 0; i < 4; ++i) {
      int r = wm + i * 16 + ln;
      int chunk = (kc * 4 + q8) ^ (ln & 7);       // r&7 == ln&7
      a[i] = *(const short8*)&Sm[r * 128 + chunk * 8];
    }
    #pragma unroll
    for (int j = 0; j < 2; ++j) {
      short8 bpv = *(const short8*)(wA + (we + j * 16 + ln) * 128 + kc * 32 + q8 * 8);
      #pragma unroll
      for (int i = 0; i < 4; ++i)
        aP[i][j] = __builtin_amdgcn_mfma_f32_16x16x32_bf16(a[i], bpv, aP[i][j], 0, 0, 0);
    }
    if (unit < 2) {
      #pragma unroll
      for (int j = 0; j < 2; ++j) {
        short8 bgv = *(const short8*)(wB + (we + j * 16 + ln) * 128 + kc * 32 + q8 * 8);
        #pragma unroll
        for (int i = 0; i < 4; ++i)
          aG[i][j] = __builtin_amdgcn_mfma_f32_16x16x32_bf16(a[i], bgv, aG[i][j], 0, 0, 0);
      }
    }
  }
  __syncthreads();   // all Abf reads done -> stg overlay safe

  // epilogue -> per-wave stg (32 e-rows x 64 m-cols, pitch 68) -> coalesced store
  unsigned short* mystg = Sm + w * 2176;
  if (unit < 2) {
    const float* gwP = g_gw  + (unit * 2) * 128;
    const float* bwP = g_bwt + (unit * 2) * 128;
    const float* gwG = g_gw  + (unit * 2 + 1) * 128;
    const float* bwG = g_bwt + (unit * 2 + 1) * 128;
    #pragma unroll
    for (int j = 0; j < 2; ++j) {
      int eg = we + j * 16 + ln;
      float gp = gwP[eg], bp = bwP[eg], gg = gwG[eg], bg = bwG[eg];
      #pragma unroll
      for (int i = 0; i < 4; ++i) {
        float vv[4];
        #pragma unroll
        for (int r = 0; r < 4; ++r) {
          int m = wm + i * 16 + q8 * 4 + r;
          float rs = Rs[m], rm = Rm[m];
          float vp = rs * aP[i][j][r] - rm * gp + bp;
          float vg = rs * aG[i][j][r] - rm * gg + bg;
          vv[r] = vp * sigm(vg) * Mlds[m];
        }
        unsigned int* du = (unsigned int*)&mystg[(j * 16 + ln) * 68 + i * 16 + q8 * 4];
        du[0] = pkbf2(vv[0], vv[1]);
        du[1] = pkbf2(vv[2], vv[3]);
      }
    }
  } else {
    const float* gw4 = g_gw  + 4 * 128;
    const float* bw4 = g_bwt + 4 * 128;
    #pragma unroll
    for (int j = 0; j < 2; ++j) {
      int eg = we + j * 16 + ln;
      float gp = gw4[eg], bp = bw4[eg];
      #pragma unroll
      for (int i = 0; i < 4; ++i) {
        float vv[4];
        #pragma unroll
        for (int r = 0; r < 4; ++r) {
          int m = wm + i * 16 + q8 * 4 + r;
          vv[r] = sigm(Rs[m] * aP[i][j][r] - Rm[m] * gp + bp);
        }
        unsigned int* du = (unsigned int*)&mystg[(j * 16 + ln) * 68 + i * 16 + q8 * 4];
        du[0] = pkbf2(vv[0], vv[1]);
        du[1] = pkbf2(vv[2], vv[3]);
      }
    }
  }

  unsigned short* dstbase = (unit == 0) ? left_t : (unit == 1 ? right_bt : gate_t);
  #pragma unroll
  for (int itr = 0; itr < 4; ++itr) {       // coalesced transposed store: rows = e
    int row = itr * 8 + (lane >> 3);        // 0..31
    int c = lane & 7;
    short8 vv = *(const short8*)&mystg[row * 68 + c * 8];
    long eg = we + row;
    *(short8*)(dstbase + eg * PP + soff + wm + c * 8) = vv;
  }
}

// ---------------- k2: per-channel 512^3 bf16 GEMM + fused gate ---------------
// Writes tmpg pre-gated: tmpg[d][i,k] = (left@right^T)[i,k] * gate[d][i,k]
__launch_bounds__(512, 4)
__global__ void k2_einsum(const unsigned short* __restrict__ left_t,
                          const unsigned short* __restrict__ right_bt,
                          const unsigned short* __restrict__ gate_t,
                          unsigned short* __restrict__ tmpg) {
  __shared__ __align__(16) unsigned short Sm[16896];
  unsigned short* Cl = Sm;
  const int t = threadIdx.x;
  const int d = blockIdx.y;
  const int i0 = (blockIdx.x >> 2) << 7;
  const int k0 = (blockIdx.x & 3) << 7;
  const unsigned short* Ag = left_t   + (long)d * PP;  // [i][j]
  const unsigned short* Bg = right_bt + (long)d * PP;  // [k][j]  (B^T)
  const unsigned short* Gg = gate_t   + (long)d * PP;  // [i][k]
  const int lane = t & 63, w = t >> 6;
  const int ln = lane & 15, q8 = lane >> 4;
  const int wm = (w >> 2) << 6, wn = (w & 3) << 5;     // 64x32 per-wave tile
  const int sr = t >> 2, sc = t & 3;

  const long aBase = (long)(i0 + sr) * NN + sc * 8;
  const long bBase = (long)(k0 + sr) * NN + sc * 8;

  auto STAGE = [&](int set, int jj) {
    gload_lds16(Ag + aBase + jj, &Sm[set * 8192 + t * 8]);
    gload_lds16(Bg + bBase + jj, &Sm[set * 8192 + 4096 + t * 8]);
  };

  floatx4 acc[4][2] = {};
  STAGE(0, 0);
  __syncthreads();
  for (int it = 0; it < 16; ++it) {
    const int cur = it & 1;
    if (it < 15) STAGE(cur ^ 1, (it + 1) * 32);      // prefetch next tile
    unsigned short* Al = Sm + cur * 8192;
    unsigned short* Bl = Al + 4096;
    short8 a[4], b[2];
    #pragma unroll
    for (int i = 0; i < 4; ++i)
      a[i] = *(const short8*)&Al[(wm + i * 16 + ln) * 32 + q8 * 8];
    #pragma unroll
    for (int j = 0; j < 2; ++j)
      b[j] = *(const short8*)&Bl[(wn + j * 16 + ln) * 32 + q8 * 8];
    #pragma unroll
    for (int i = 0; i < 4; ++i)
      #pragma unroll
      for (int j = 0; j < 2; ++j)
        acc[i][j] = __builtin_amdgcn_mfma_f32_16x16x32_bf16(a[i], b[j], acc[i][j], 0, 0, 0);
    __syncthreads();
  }
  // gate in f32, restage C through LDS -> coalesced bf16 stores
  #pragma unroll
  for (int i = 0; i < 4; ++i)
    #pragma unroll
    for (int j = 0; j < 2; ++j) {
      int n = wn + j * 16 + ln;
      #pragma unroll
      for (int r = 0; r < 4; ++r) {
        int m = wm + i * 16 + q8 * 4 + r;
        float gf = bf2f(Gg[(long)(i0 + m) * NN + k0 + n]);
        Cl[m * 132 + n] = f2bf(acc[i][j][r] * gf);
      }
    }
  __syncthreads();
  unsigned short* Og = tmpg + (long)d * PP;
  #pragma unroll
  for (int it = 0; it < 4; ++it) {
    int flat = it * 512 + t;
    int m = flat >> 4, c = flat & 15;
    *(short8*)(Og + (long)(i0 + m) * NN + k0 + c * 8) = *(const short8*)&Cl[m * 132 + c * 8];
  }
}

// ---------------- k3: out[p][e] = sum_d tmpg[d][p]*wo[d][e] + b_o ------------
__launch_bounds__(512, 4)
__global__ void k3_out(const unsigned short* __restrict__ tmpg,
                       const unsigned short* __restrict__ wt,
                       const float* __restrict__ b_o,
                       float* __restrict__ out) {
  __shared__ __align__(16) unsigned short Tl[128 * 144];  // [p][d], 36.9 KB
  unsigned int* TlU = (unsigned int*)Tl;                  // pitch 72 uints
  const int t = threadIdx.x;
  const long p0 = (long)blockIdx.x << 7;
  const unsigned short* wo = wt + 5 * 16384;

  #pragma unroll
  for (int it = 0; it < 2; ++it) {
    int flat = it * 512 + t;
    int rp = flat >> 4;      // d-pair 0..63
    int c  = flat & 15;      // 16B chunk along p
    const unsigned short* ra = tmpg + (long)(2 * rp) * PP + p0 + c * 8;
    uintx4 xa = *(const uintx4*)ra;          // row d=2rp
    uintx4 xb = *(const uintx4*)(ra + PP);   // row d=2rp+1
    int sw = ((c & 7) << 3) ^ ((c >> 3) << 2);
    #pragma unroll
    for (int cc = 0; cc < 4; ++cc) {
      int p = c * 8 + 2 * cc;
      TlU[p * 72 + (rp ^ sw)]       = (xa[cc] & 0xffffu) | (xb[cc] << 16);
      TlU[(p + 1) * 72 + (rp ^ sw)] = (xa[cc] >> 16) | (xb[cc] & 0xffff0000u);
    }
  }
  __syncthreads();

  const int lane = t & 63, w = t >> 6;
  const int ln = lane & 15, q8 = lane >> 4;
  const int wm = (w >> 2) << 6, wn = (w & 3) << 5;    // 64x32 per-wave tile

  floatx4 acc[4][2] = {};
  #pragma unroll
  for (int ks = 0; ks < 4; ++ks) {
    short8 a[4], b[2];
    #pragma unroll
    for (int i = 0; i < 4; ++i) {
      int p = wm + i * 16 + ln;
      int swh = (((p >> 3) & 7) << 4) ^ (((p >> 6) & 1) << 3);  // short units
      a[i] = *(const short8*)&Tl[p * 144 + ((ks * 32 + q8 * 8) ^ swh)];
    }
    #pragma unroll
    for (int j = 0; j < 2; ++j)
      b[j] = *(const short8*)(wo + (wn + j * 16 + ln) * 128 + ks * 32 + q8 * 8);
    #pragma unroll
    for (int i = 0; i < 4; ++i)
      #pragma unroll
      for (int j = 0; j < 2; ++j)
        acc[i][j] = __builtin_amdgcn_mfma_f32_16x16x32_bf16(a[i], b[j], acc[i][j], 0, 0, 0);
  }
  #pragma unroll
  for (int j = 0; j < 2; ++j) {
    int eg = wn + j * 16 + ln;
    float bias = b_o[eg];
    #pragma unroll
    for (int i = 0; i < 4; ++i)
      #pragma unroll
      for (int r = 0; r < 4; ++r) {
        int m = wm + i * 16 + q8 * 4 + r;
        out[(p0 + m) * DD + eg] = acc[i][j][r] + bias;
      }
  }
}

extern "C" void kernel_launch(void* const* d_in, const int* in_sizes, int n_in,
                              void* d_out, int out_size, void* d_ws, size_t ws_size,
                              hipStream_t stream) {
  const float* pair = (const float*)d_in[0];
  const float* pmask = (const float*)d_in[1];
  const float* ln_g = (const float*)d_in[2];
  const float* ln_b = (const float*)d_in[3];
  const float* w_lp = (const float*)d_in[4];
  const float* b_lp = (const float*)d_in[5];
  const float* w_lg = (const float*)d_in[6];
  const float* b_lg = (const float*)d_in[7];
  const float* w_rp = (const float*)d_in[8];
  const float* b_rp = (const float*)d_in[9];
  const float* w_rg = (const float*)d_in[10];
  const float* b_rg = (const float*)d_in[11];
  const float* w_g  = (const float*)d_in[12];
  const float* b_g  = (const float*)d_in[13];
  const float* w_o  = (const float*)d_in[14];
  const float* b_o  = (const float*)d_in[15];
  float* out = (float*)d_out;

  // workspace: wt(192KB) + tmpg + left_t + right_bt + gate_t (layout unchanged)
  char* ws = (char*)d_ws;
  unsigned short* wt       = (unsigned short*)ws;
  unsigned short* tmpg     = (unsigned short*)(ws + 196608);
  unsigned short* left_t   = tmpg     + (size_t)PP * DD;
  unsigned short* right_bt = left_t   + (size_t)PP * DD;
  unsigned short* gate_t   = right_bt + (size_t)PP * DD;

  k0_prep<<<dim3(64, 6), 256, 0, stream>>>(w_lp, w_lg, w_rp, w_rg, w_g, w_o, wt);
  k0b_gw<<<dim3(5), 128, 0, stream>>>(ln_g, ln_b, wt, b_lp, b_lg, b_rp, b_rg, b_g);
  k1b_proj<<<dim3(2048, 3), 512, 0, stream>>>(pair, pmask, ln_g, wt,
      left_t, right_bt, gate_t);
  k2_einsum<<<dim3(16, 128), 512, 0, stream>>>(left_t, right_bt, gate_t, tmpg);
  k3_out<<<dim3(2048), 512, 0, stream>>>(tmpg, wt, b_o, out);
}

// Round 5
// 477.091 us; speedup vs baseline: 1.1880x; 1.1880x over previous
//
#include <hip/hip_runtime.h>

#define NN 512
#define DD 128
#define PP (NN*NN)   // 262144 positions

typedef __attribute__((ext_vector_type(8))) short short8;
typedef __attribute__((ext_vector_type(4))) float floatx4;
typedef __attribute__((ext_vector_type(4))) unsigned int uintx4;
typedef __attribute__((ext_vector_type(2))) unsigned int uintx2;

__device__ __forceinline__ unsigned short f2bf(float f) {
  unsigned int u = __float_as_uint(f);
  u += 0x7fffu + ((u >> 16) & 1u);          // RNE
  return (unsigned short)(u >> 16);
}
__device__ __forceinline__ float bf2f(unsigned short h) {
  return __uint_as_float(((unsigned int)h) << 16);
}
// packed f32x2 -> bf16x2 (hardware RNE), low half <- first arg
__device__ __forceinline__ unsigned int pkbf2(float lo, float hi) {
  unsigned int r;
  asm("v_cvt_pk_bf16_f32 %0, %1, %2" : "=v"(r) : "v"(lo), "v"(hi));
  return r;
}
__device__ __forceinline__ float sigm(float x) {
  return 1.f / (1.f + __expf(-x));
}

// async global->LDS, 16B per lane. LDS dest must be wave-uniform base + lane*16.
__device__ __forceinline__ void gload_lds16(const unsigned short* g, unsigned short* l) {
  __builtin_amdgcn_global_load_lds(
      (const __attribute__((address_space(1))) unsigned int*)g,
      (__attribute__((address_space(3))) unsigned int*)l, 16, 0, 0);
}

// ---------------- k0: weights f32 [d][e] -> bf16 [m][e][d] ----------------
__global__ void k0_prep(const float* __restrict__ wlp, const float* __restrict__ wlg,
                        const float* __restrict__ wrp, const float* __restrict__ wrg,
                        const float* __restrict__ wg,  const float* __restrict__ wo,
                        unsigned short* __restrict__ wt) {
  const float* src[6] = {wlp, wlg, wrp, wrg, wg, wo};
  int m = blockIdx.y;
  int idx = blockIdx.x * 256 + threadIdx.x;   // 0..16383
  int d = idx >> 7, e = idx & 127;
  wt[m * 16384 + e * 128 + d] = f2bf(src[m][d * 128 + e]);
}

// ---------------- k1a: LayerNorm pair f32 -> xln bf16 [p][d] -----------------
// Coalesced layout: 32 lanes per row (each lane owns 4 floats), wave = 2 rows.
__launch_bounds__(256, 8)
__global__ void k1a_ln(const float* __restrict__ pair,
                       const float* __restrict__ lng, const float* __restrict__ lnb,
                       unsigned short* __restrict__ xln) {
  const int t = threadIdx.x;
  const int sub = t & 31;                       // float4 slot within row
  const long row0 = (long)blockIdx.x * 128 + (t >> 5);  // 8 rows per 256t pass
  const floatx4 g4 = *(const floatx4*)(lng + sub * 4);
  const floatx4 b4 = *(const floatx4*)(lnb + sub * 4);
  const float* src = pair + row0 * DD + sub * 4;
  unsigned short* dst = xln + row0 * DD + sub * 4;
  floatx4 vn = *(const floatx4*)src;
  #pragma unroll
  for (int pass = 0; pass < 16; ++pass) {
    floatx4 v = vn;
    if (pass < 15) vn = *(const floatx4*)(src + (pass + 1) * 8 * DD);
    float s  = v.x + v.y + v.z + v.w;
    float s2 = v.x * v.x + v.y * v.y + v.z * v.z + v.w * v.w;
    #pragma unroll
    for (int m = 1; m < 32; m <<= 1) {
      s  += __shfl_xor(s, m);
      s2 += __shfl_xor(s2, m);
    }
    float mu = s * (1.f / 128.f);
    float rs = rsqrtf(s2 * (1.f / 128.f) - mu * mu + 1e-5f);
    uintx2 o;
    o[0] = pkbf2((v.x - mu) * rs * g4.x + b4.x, (v.y - mu) * rs * g4.y + b4.y);
    o[1] = pkbf2((v.z - mu) * rs * g4.z + b4.z, (v.w - mu) * rs * g4.w + b4.w);
    *(uintx2*)(dst + pass * 8 * DD) = o;
  }
}

// ---------------- k1b: projections, 2-phase double-buffered staged GEMM ------
// unit 0: left_t[e][p], unit 1: right_bt[e][k*512+j], unit 2: gate_t[e][p]
__launch_bounds__(512, 4)
__global__ void k1b_proj(const unsigned short* __restrict__ xln,
                         const float* __restrict__ pmask,
                         const unsigned short* __restrict__ wt,
                         const float* __restrict__ b_lp, const float* __restrict__ b_lg,
                         const float* __restrict__ b_rp, const float* __restrict__ b_rg,
                         const float* __restrict__ b_g,
                         unsigned short* __restrict__ left_t,
                         unsigned short* __restrict__ right_bt,
                         unsigned short* __restrict__ gate_t) {
  // 2 sets x (Al 4096 + Bp 4096 + Bg 4096) shorts = 49152 B; epilogue stg
  // (8 waves x 2176 shorts = 34.8 KB) overlays the sets after the last barrier.
  __shared__ __align__(16) unsigned short Sm[24576];
  __shared__ float Mlds[128];

  const int t = threadIdx.x;
  const int unit = blockIdx.y;
  const int q = blockIdx.x;

  int j0 = 0, kk = 0;
  long p0 = 0, soff;
  if (unit == 1) {
    j0 = (q >> 9) << 7; kk = q & 511;
    soff = (long)kk * NN + j0;
  } else {
    p0 = (long)q << 7;
    soff = p0;
  }
  auto arow = [&](int r) -> long {
    return (unit == 1) ? ((long)(j0 + r) * NN + kk) : (p0 + r);
  };

  if (unit < 2 && t < 128) Mlds[t] = pmask[arow(t)];

  const unsigned short* wA = wt + (unit == 0 ? 0 : unit == 1 ? 2 : 4) * 16384;
  const unsigned short* wB = wt + (unit == 0 ? 1 : 3) * 16384;  // unused for unit 2

  const int lane = t & 63, w = t >> 6;            // 8 waves
  const int ln = lane & 15, q8 = lane >> 4;
  const int wm = (w >> 2) << 6, we = (w & 3) << 5; // 64x32 per-wave tile
  const int sr = t >> 2, sc = t & 3;               // staging: one 16B chunk/thread

  const long aBase = arow(sr) * DD + sc * 8;       // invariant part of A address

  auto STAGE = [&](int set, int kc) {
    unsigned short* base = Sm + set * 12288;
    gload_lds16(xln + aBase + kc * 32,            &base[t * 8]);
    gload_lds16(wA + sr * 128 + kc * 32 + sc * 8, &base[4096 + t * 8]);
    if (unit < 2)
      gload_lds16(wB + sr * 128 + kc * 32 + sc * 8, &base[8192 + t * 8]);
  };

  floatx4 aP[4][2] = {}, aG[4][2] = {};
  STAGE(0, 0);
  __syncthreads();
  #pragma unroll
  for (int kc = 0; kc < 4; ++kc) {
    const int cur = kc & 1;
    if (kc < 3) STAGE(cur ^ 1, kc + 1);          // prefetch next tile
    unsigned short* Al = Sm + cur * 12288;
    unsigned short* Bp = Al + 4096;
    unsigned short* Bg = Al + 8192;
    short8 a[4];
    #pragma unroll
    for (int i = 0; i < 4; ++i)
      a[i] = *(const short8*)&Al[(wm + i * 16 + ln) * 32 + q8 * 8];
    #pragma unroll
    for (int j = 0; j < 2; ++j) {
      short8 bpv = *(const short8*)&Bp[(we + j * 16 + ln) * 32 + q8 * 8];
      #pragma unroll
      for (int i = 0; i < 4; ++i)
        aP[i][j] = __builtin_amdgcn_mfma_f32_16x16x32_bf16(a[i], bpv, aP[i][j], 0, 0, 0);
    }
    if (unit < 2) {
      #pragma unroll
      for (int j = 0; j < 2; ++j) {
        short8 bgv = *(const short8*)&Bg[(we + j * 16 + ln) * 32 + q8 * 8];
        #pragma unroll
        for (int i = 0; i < 4; ++i)
          aG[i][j] = __builtin_amdgcn_mfma_f32_16x16x32_bf16(a[i], bgv, aG[i][j], 0, 0, 0);
      }
    }
    __syncthreads();   // drains this iteration's prefetch loads after compute
  }

  // epilogue -> per-wave stg (32 e-rows x 64 m-cols, pitch 68) -> coalesced store
  unsigned short* mystg = Sm + w * 2176;
  if (unit < 2) {
    const float* bpp = (unit == 0) ? b_lp : b_rp;
    const float* bgg = (unit == 0) ? b_lg : b_rg;
    #pragma unroll
    for (int j = 0; j < 2; ++j) {
      int eg = we + j * 16 + ln;
      float bp = bpp[eg], bg = bgg[eg];
      #pragma unroll
      for (int i = 0; i < 4; ++i) {
        float vv[4];
        #pragma unroll
        for (int r = 0; r < 4; ++r) {
          int m = wm + i * 16 + q8 * 4 + r;
          vv[r] = (aP[i][j][r] + bp) * sigm(aG[i][j][r] + bg) * Mlds[m];
        }
        unsigned int* du = (unsigned int*)&mystg[(j * 16 + ln) * 68 + i * 16 + q8 * 4];
        du[0] = pkbf2(vv[0], vv[1]);
        du[1] = pkbf2(vv[2], vv[3]);
      }
    }
  } else {
    #pragma unroll
    for (int j = 0; j < 2; ++j) {
      int eg = we + j * 16 + ln;
      float bg = b_g[eg];
      #pragma unroll
      for (int i = 0; i < 4; ++i) {
        float vv[4];
        #pragma unroll
        for (int r = 0; r < 4; ++r)
          vv[r] = sigm(aP[i][j][r] + bg);
        unsigned int* du = (unsigned int*)&mystg[(j * 16 + ln) * 68 + i * 16 + q8 * 4];
        du[0] = pkbf2(vv[0], vv[1]);
        du[1] = pkbf2(vv[2], vv[3]);
      }
    }
  }

  unsigned short* dstbase = (unit == 0) ? left_t : (unit == 1 ? right_bt : gate_t);
  #pragma unroll
  for (int itr = 0; itr < 4; ++itr) {       // coalesced transposed store: rows = e
    int row = itr * 8 + (lane >> 3);        // 0..31
    int c = lane & 7;
    short8 vv = *(const short8*)&mystg[row * 68 + c * 8];
    long eg = we + row;
    *(short8*)(dstbase + eg * PP + soff + wm + c * 8) = vv;
  }
}

// ---------------- k2: per-channel 512^3 bf16 GEMM + fused gate ---------------
// Writes tmpg pre-gated: tmpg[d][i,k] = (left@right^T)[i,k] * gate[d][i,k]
// XCD-chunked swizzle: hw block id h -> XCD h%8; logical L = (h%8)*256 + h/8
// puts all 16 (i,k)-tiles of each d (and 16 consecutive d) on ONE XCD, so the
// per-d A/B/G panels (1.5 MB) are L2-resident and fetched from HBM once
// instead of 4x. Bijective since 2048 % 8 == 0.
__launch_bounds__(512, 4)
__global__ void k2_einsum(const unsigned short* __restrict__ left_t,
                          const unsigned short* __restrict__ right_bt,
                          const unsigned short* __restrict__ gate_t,
                          unsigned short* __restrict__ tmpg) {
  __shared__ __align__(16) unsigned short Sm[16896];
  unsigned short* Cl = Sm;
  const int t = threadIdx.x;
  const int h = blockIdx.x;
  const int L = (h & 7) * 256 + (h >> 3);   // XCD-chunked logical id
  const int d = L >> 4;
  const int tile = L & 15;
  const int i0 = (tile >> 2) << 7;
  const int k0 = (tile & 3) << 7;
  const unsigned short* Ag = left_t   + (long)d * PP;  // [i][j]
  const unsigned short* Bg = right_bt + (long)d * PP;  // [k][j]  (B^T)
  const unsigned short* Gg = gate_t   + (long)d * PP;  // [i][k]
  const int lane = t & 63, w = t >> 6;
  const int ln = lane & 15, q8 = lane >> 4;
  const int wm = (w >> 2) << 6, wn = (w & 3) << 5;     // 64x32 per-wave tile
  const int sr = t >> 2, sc = t & 3;

  const long aBase = (long)(i0 + sr) * NN + sc * 8;
  const long bBase = (long)(k0 + sr) * NN + sc * 8;

  auto STAGE = [&](int set, int jj) {
    gload_lds16(Ag + aBase + jj, &Sm[set * 8192 + t * 8]);
    gload_lds16(Bg + bBase + jj, &Sm[set * 8192 + 4096 + t * 8]);
  };

  floatx4 acc[4][2] = {};
  STAGE(0, 0);
  __syncthreads();
  for (int it = 0; it < 16; ++it) {
    const int cur = it & 1;
    if (it < 15) STAGE(cur ^ 1, (it + 1) * 32);      // prefetch next tile
    unsigned short* Al = Sm + cur * 8192;
    unsigned short* Bl = Al + 4096;
    short8 a[4], b[2];
    #pragma unroll
    for (int i = 0; i < 4; ++i)
      a[i] = *(const short8*)&Al[(wm + i * 16 + ln) * 32 + q8 * 8];
    #pragma unroll
    for (int j = 0; j < 2; ++j)
      b[j] = *(const short8*)&Bl[(wn + j * 16 + ln) * 32 + q8 * 8];
    #pragma unroll
    for (int i = 0; i < 4; ++i)
      #pragma unroll
      for (int j = 0; j < 2; ++j)
        acc[i][j] = __builtin_amdgcn_mfma_f32_16x16x32_bf16(a[i], b[j], acc[i][j], 0, 0, 0);
    __syncthreads();
  }
  // gate in f32, restage C through LDS -> coalesced bf16 stores
  #pragma unroll
  for (int i = 0; i < 4; ++i)
    #pragma unroll
    for (int j = 0; j < 2; ++j) {
      int n = wn + j * 16 + ln;
      #pragma unroll
      for (int r = 0; r < 4; ++r) {
        int m = wm + i * 16 + q8 * 4 + r;
        float gf = bf2f(Gg[(long)(i0 + m) * NN + k0 + n]);
        Cl[m * 132 + n] = f2bf(acc[i][j][r] * gf);
      }
    }
  __syncthreads();
  unsigned short* Og = tmpg + (long)d * PP;
  #pragma unroll
  for (int it = 0; it < 4; ++it) {
    int flat = it * 512 + t;
    int m = flat >> 4, c = flat & 15;
    *(short8*)(Og + (long)(i0 + m) * NN + k0 + c * 8) = *(const short8*)&Cl[m * 132 + c * 8];
  }
}

// ---------------- k3: out[p][e] = sum_d tmpg[d][p]*wo[d][e] + b_o ------------
// tmpg is pre-gated by k2. Transpose-on-stage into Tl[p][d] (pitch 144 shorts)
// with XOR bank swizzle; repack is pure bit-ops (values already bf16).
__launch_bounds__(512, 4)
__global__ void k3_out(const unsigned short* __restrict__ tmpg,
                       const unsigned short* __restrict__ wt,
                       const float* __restrict__ b_o,
                       float* __restrict__ out) {
  __shared__ __align__(16) unsigned short Tl[128 * 144];  // [p][d], 36.9 KB
  unsigned int* TlU = (unsigned int*)Tl;                  // pitch 72 uints
  const int t = threadIdx.x;
  const long p0 = (long)blockIdx.x << 7;
  const unsigned short* wo = wt + 5 * 16384;

  #pragma unroll
  for (int it = 0; it < 2; ++it) {
    int flat = it * 512 + t;
    int rp = flat >> 4;      // d-pair 0..63
    int c  = flat & 15;      // 16B chunk along p
    const unsigned short* ra = tmpg + (long)(2 * rp) * PP + p0 + c * 8;
    uintx4 xa = *(const uintx4*)ra;          // row d=2rp
    uintx4 xb = *(const uintx4*)(ra + PP);   // row d=2rp+1
    int sw = ((c & 7) << 3) ^ ((c >> 3) << 2);
    #pragma unroll
    for (int cc = 0; cc < 4; ++cc) {
      int p = c * 8 + 2 * cc;
      TlU[p * 72 + (rp ^ sw)]       = (xa[cc] & 0xffffu) | (xb[cc] << 16);
      TlU[(p + 1) * 72 + (rp ^ sw)] = (xa[cc] >> 16) | (xb[cc] & 0xffff0000u);
    }
  }
  __syncthreads();

  const int lane = t & 63, w = t >> 6;
  const int ln = lane & 15, q8 = lane >> 4;
  const int wm = (w >> 2) << 6, wn = (w & 3) << 5;    // 64x32 per-wave tile

  floatx4 acc[4][2] = {};
  #pragma unroll
  for (int ks = 0; ks < 4; ++ks) {
    short8 a[4], b[2];
    #pragma unroll
    for (int i = 0; i < 4; ++i) {
      int p = wm + i * 16 + ln;
      int swh = (((p >> 3) & 7) << 4) ^ (((p >> 6) & 1) << 3);  // short units
      a[i] = *(const short8*)&Tl[p * 144 + ((ks * 32 + q8 * 8) ^ swh)];
    }
    #pragma unroll
    for (int j = 0; j < 2; ++j)
      b[j] = *(const short8*)(wo + (wn + j * 16 + ln) * 128 + ks * 32 + q8 * 8);
    #pragma unroll
    for (int i = 0; i < 4; ++i)
      #pragma unroll
      for (int j = 0; j < 2; ++j)
        acc[i][j] = __builtin_amdgcn_mfma_f32_16x16x32_bf16(a[i], b[j], acc[i][j], 0, 0, 0);
  }
  #pragma unroll
  for (int j = 0; j < 2; ++j) {
    int eg = wn + j * 16 + ln;
    float bias = b_o[eg];
    #pragma unroll
    for (int i = 0; i < 4; ++i)
      #pragma unroll
      for (int r = 0; r < 4; ++r) {
        int m = wm + i * 16 + q8 * 4 + r;
        out[(p0 + m) * DD + eg] = acc[i][j][r] + bias;
      }
  }
}

extern "C" void kernel_launch(void* const* d_in, const int* in_sizes, int n_in,
                              void* d_out, int out_size, void* d_ws, size_t ws_size,
                              hipStream_t stream) {
  const float* pair = (const float*)d_in[0];
  const float* pmask = (const float*)d_in[1];
  const float* ln_g = (const float*)d_in[2];
  const float* ln_b = (const float*)d_in[3];
  const float* w_lp = (const float*)d_in[4];
  const float* b_lp = (const float*)d_in[5];
  const float* w_lg = (const float*)d_in[6];
  const float* b_lg = (const float*)d_in[7];
  const float* w_rp = (const float*)d_in[8];
  const float* b_rp = (const float*)d_in[9];
  const float* w_rg = (const float*)d_in[10];
  const float* b_rg = (const float*)d_in[11];
  const float* w_g  = (const float*)d_in[12];
  const float* b_g  = (const float*)d_in[13];
  const float* w_o  = (const float*)d_in[14];
  const float* b_o  = (const float*)d_in[15];
  float* out = (float*)d_out;

  // workspace: wt(192KB) + xln (later tmpg) + left_t + right_bt + gate_t
  char* ws = (char*)d_ws;
  unsigned short* wt       = (unsigned short*)ws;
  unsigned short* xln      = (unsigned short*)(ws + 196608);
  unsigned short* left_t   = xln      + (size_t)PP * DD;
  unsigned short* right_bt = left_t   + (size_t)PP * DD;
  unsigned short* gate_t   = right_bt + (size_t)PP * DD;
  unsigned short* tmpg     = xln;   // xln dead after k1b

  k0_prep<<<dim3(64, 6), 256, 0, stream>>>(w_lp, w_lg, w_rp, w_rg, w_g, w_o, wt);
  k1a_ln<<<dim3(2048), 256, 0, stream>>>(pair, ln_g, ln_b, xln);
  k1b_proj<<<dim3(2048, 3), 512, 0, stream>>>(xln, pmask, wt,
      b_lp, b_lg, b_rp, b_rg, b_g, left_t, right_bt, gate_t);
  k2_einsum<<<dim3(2048), 512, 0, stream>>>(left_t, right_bt, gate_t, tmpg);
  k3_out<<<dim3(2048), 512, 0, stream>>>(tmpg, wt, b_o, out);
}